// Round 24
// baseline (107.355 us; speedup 1.0000x reference)
//
#include <hip/hip_runtime.h>
#include <hip/hip_bf16.h>

#define DD 1024            // fp8 elems per row (= bytes)
#define BM 128
#define BN 128
#define BK 128             // fp8 elems per K-tile -> 128 B rows (proven geometry)
#define NKT (DD / BK)      // 8 K-tiles
#define TAU 32.0f
#define PTH 0.1f
#define BIGF 3.0e38f

typedef __attribute__((ext_vector_type(4))) float f32x4;
typedef __attribute__((ext_vector_type(2))) long i64x2;

// f32 -> OCP e4m3fn (RNE, saturate to 448, subnormal support)
__device__ __forceinline__ unsigned char f2e4m3(float f) {
  unsigned u = __float_as_uint(f);
  unsigned s = (u >> 24) & 0x80u;
  unsigned au = u & 0x7fffffffu;
  if (au >= 0x43E00000u) return (unsigned char)(s | 0x7E);     // clamp >= 448
  if (au < 0x3C800000u) {                                      // |f| < 2^-6: subnormal
    int m = (int)rintf(__uint_as_float(au) * 512.0f);          // steps of 2^-9
    if (m > 7) return (unsigned char)(s | 0x08);
    return (unsigned char)(s | (unsigned)m);
  }
  unsigned tmp = au + 0x0007FFFFu + ((au >> 20) & 1u);         // RNE at mantissa bit 20
  unsigned e4 = (tmp >> 23) - 120u;                            // rebias 127 -> 7
  if (e4 >= 16u) return (unsigned char)(s | 0x7E);
  return (unsigned char)(s | (e4 << 3) | ((tmp >> 20) & 7u));
}

// sorted-ascending top-5-smallest insert via med3: 5 independent VALU ops
__device__ __forceinline__ void insert5(float (&t)[5], float v) {
  float t0 = t[0], t1 = t[1], t2 = t[2], t3 = t[3], t4 = t[4];
  t[0] = fminf(t0, v);
  t[1] = __builtin_amdgcn_fmed3f(v, t0, t1);
  t[2] = __builtin_amdgcn_fmed3f(v, t1, t2);
  t[3] = __builtin_amdgcn_fmed3f(v, t2, t3);
  t[4] = __builtin_amdgcn_fmed3f(v, t3, t4);
}

// merge two ascending 5-lists -> ascending top-5 of union (~22 VALU):
// c_i = min(a_i, b_i, min_{j+k=i-1} max(a_j, b_k))
__device__ __forceinline__ void merge5(float (&a)[5], const float (&b)[5]) {
  float c0 = fminf(a[0], b[0]);
  float m00 = fmaxf(a[0], b[0]);
  float c1 = fminf(fminf(a[1], b[1]), m00);
  float m01 = fmaxf(a[0], b[1]), m10 = fmaxf(a[1], b[0]);
  float c2 = fminf(fminf(a[2], b[2]), fminf(m01, m10));
  float m02 = fmaxf(a[0], b[2]), m11 = fmaxf(a[1], b[1]), m20 = fmaxf(a[2], b[0]);
  float c3 = fminf(fminf(a[3], b[3]), fminf(fminf(m02, m11), m20));
  float m03 = fmaxf(a[0], b[3]), m12 = fmaxf(a[1], b[2]);
  float m21 = fmaxf(a[2], b[1]), m30 = fmaxf(a[3], b[0]);
  float c4 = fminf(fminf(a[4], b[4]), fminf(fminf(m03, m12), fminf(m21, m30)));
  a[0] = c0; a[1] = c1; a[2] = c2; a[3] = c3; a[4] = c4;
}

__device__ __forceinline__ void gload16(const unsigned char* g, unsigned char* l) {
  __builtin_amdgcn_global_load_lds(
      (const __attribute__((address_space(1))) void*)g,
      (__attribute__((address_space(3))) void*)l, 16, 0, 0);
}

// one wave per row: squared norm (f32, exact) + fp8 cast, K bit-field-permuted:
// within each 128-block, position p holds logical k with q[3:4]<->q[5:6] swapped
// (self-inverse; identical permutation on both GEMM operands => X.X^T unchanged).
__global__ void prep_kernel(const float* __restrict__ x, unsigned char* __restrict__ x8,
                            float* __restrict__ sq) {
  const int row  = blockIdx.x * 4 + (threadIdx.x >> 6);
  const int lane = threadIdx.x & 63;
  const float4* xr = reinterpret_cast<const float4*>(x) + (size_t)row * (DD / 4);
  float s = 0.f;
  #pragma unroll
  for (int i = 0; i < 4; ++i) {
    float4 v = xr[lane + 64 * i];
    s += v.x * v.x + v.y * v.y + v.z * v.z + v.w * v.w;
    uchar4 b;
    b.x = f2e4m3(v.x); b.y = f2e4m3(v.y); b.z = f2e4m3(v.z); b.w = f2e4m3(v.w);
    const int k0 = (lane + 64 * i) * 4;
    const int q  = k0 & 127;
    const int p  = (k0 & ~127) + ((q >> 3) & 3) * 32 + ((q >> 5) & 3) * 8 + (q & 7);
    *reinterpret_cast<uchar4*>(x8 + (size_t)row * DD + p) = b;
  }
  #pragma unroll
  for (int off = 32; off > 0; off >>= 1) s += __shfl_xor(s, off, 64);
  if (lane == 0) sq[row] = s;
}

// Symmetric flash top-k over upper-triangle 128x128 block-pairs (I,J), 8x8
// super-tiles + XCD swizzle. Register pipeline + setprio. LDS union capped
// at 40960 B (merge stride 161->160) -> 4 blocks/CU at unchanged VGPR=80
// (launch_bounds' 2nd arg is a min-occupancy hint; residency is resource-set).
__global__ __launch_bounds__(256, 3)
void gemm_topk_kernel(const unsigned char* __restrict__ x8, const float* __restrict__ sq,
                      float* __restrict__ partial, int N) {
  __shared__ union ShMem {
    struct { unsigned char A[BM * BK]; unsigned char B[BN * BK]; } tl;  // 32 KB
    float mrg[64 * 160];   // row-merge: row*160 + contrib*5 + j  (40 KB exactly)
    float mrgc[128 * 41];  // col-merge: col*41 + contrib*5 + j   (21 KB)
  } sh;
  static_assert(sizeof(ShMem) <= 40960, "LDS union must stay <= 40KB for 4 blocks/CU");

  const int tid  = threadIdx.x;
  const int lane = tid & 63;
  const int wid  = tid >> 6;
  const int wr   = wid >> 1;   // 0..1 -> 64-row half
  const int wc   = wid & 1;    // 0..1 -> 64-col half
  const int l15  = lane & 15;
  const int l4   = lane >> 4;  // 0..3

  const int NBv = N / BM;      // 64 block-rows
  const int NSB = NBv / 8;     // 8 super-rows

  // bijective chunked XCD swizzle (gridDim.x divisible by 8)
  const int chunk = gridDim.x >> 3;
  const int swz = (blockIdx.x & 7) * chunk + (blockIdx.x >> 3);
  const int sp  = swz >> 6;    // super-pair (triangle over NSB)
  const int sub = swz & 63;

  int SI = 0;
  #define TSTART(i) ((i) * NSB - ((i) * ((i) - 1)) / 2)
  while (SI + 1 < NSB && TSTART(SI + 1) <= sp) ++SI;
  const int SJ = SI + (sp - TSTART(SI));
  #undef TSTART
  const int si = sub >> 3, sj = sub & 7;
  if (SI == SJ && si > sj) return;  // lower-triangle sub-pair of diagonal super-pair
  const int I = SI * 8 + si, J = SJ * 8 + sj;

  const int row0 = I * BM;
  const int cb   = J * BM;
  const bool diag = (I == J);

  // DMA staging: instruction j covers rows j*8..j*8+7 (1 KB linear LDS).
  // lane -> row j*8 + (lane>>3), phys slot lane&7 holds logical slot
  // (lane&7)^(row&7); row&7 == lane>>3.
  const int lr = lane >> 3;
  const int lc = (lane & 7) ^ lr;
  const size_t offl = (size_t)lr * DD + (size_t)lc * 16;
  const int jbase = wid * 4;
  const unsigned char* srcA = x8 + (size_t)row0 * DD + offl;
  const unsigned char* srcB = x8 + (size_t)cb * DD + offl;

  f32x4 acc[4][4];
  #pragma unroll
  for (int mi = 0; mi < 4; ++mi)
    #pragma unroll
    for (int ni = 0; ni < 4; ++ni) {
      f32x4 z; z[0] = 0.f; z[1] = 0.f; z[2] = 0.f; z[3] = 0.f;
      acc[mi][ni] = z;
    }

  // fragment reads: lane's 32 contiguous logical bytes at row*BK + l4*32,
  // as two b128 chunks c=0,1 at phys slot (l4*2+c)^(row&7); row&7 == l15&7
  const int ps0 = ((l4 * 2 + 0) ^ (l15 & 7)) * 16;
  const int ps1 = ((l4 * 2 + 1) ^ (l15 & 7)) * 16;

#define STAGE(kt) { const size_t kk = (size_t)(kt) * BK;                          \
    _Pragma("unroll") for (int jj = 0; jj < 4; ++jj) {                            \
      const int j = jbase + jj;                                                   \
      gload16(srcA + (size_t)j * 8 * DD + kk, sh.tl.A + j * 1024);                \
      gload16(srcB + (size_t)j * 8 * DD + kk, sh.tl.B + j * 1024); } }

  // prologue: stage tile 0
  STAGE(0);

  for (int t = 0; t < NKT; ++t) {
    __syncthreads();   // vmcnt drain: tile t landed (issued last iter / prologue)

    // read ALL fragments of tile t into registers
    i64x2 af[4][2], bfr[4][2];
    #pragma unroll
    for (int mi = 0; mi < 4; ++mi) {
      const unsigned char* rp = sh.tl.A + (wr * 64 + mi * 16 + l15) * BK;
      af[mi][0] = *reinterpret_cast<const i64x2*>(rp + ps0);
      af[mi][1] = *reinterpret_cast<const i64x2*>(rp + ps1);
    }
    #pragma unroll
    for (int ni = 0; ni < 4; ++ni) {
      const unsigned char* rp = sh.tl.B + (wc * 64 + ni * 16 + l15) * BK;
      bfr[ni][0] = *reinterpret_cast<const i64x2*>(rp + ps0);
      bfr[ni][1] = *reinterpret_cast<const i64x2*>(rp + ps1);
    }

    __syncthreads();   // lgkm drain: all waves' fragment reads done -> buffer free

    if (t + 1 < NKT) STAGE(t + 1);  // DMA issues BEFORE the MFMA cluster: latency hides

    __builtin_amdgcn_s_setprio(1);  // favor MFMA-issuing waves vs co-resident stagers
    #pragma unroll
    for (int ks = 0; ks < 4; ++ks)
      #pragma unroll
      for (int mi = 0; mi < 4; ++mi)
        #pragma unroll
        for (int ni = 0; ni < 4; ++ni)
          acc[mi][ni] = __builtin_amdgcn_mfma_f32_16x16x32_fp8_fp8(
              af[mi][ks >> 1][ks & 1], bfr[ni][ks >> 1][ks & 1], acc[mi][ni], 0, 0, 0);
    __builtin_amdgcn_s_setprio(0);
  }

  // d^2 = sq_r + sq_c - 2*dot; fold row-side (t5r) and, off-diag, col-side (t5c)
  float t5r[16][5], t5c[4][5];
  #pragma unroll
  for (int i = 0; i < 16; ++i)
    #pragma unroll
    for (int j = 0; j < 5; ++j) t5r[i][j] = BIGF;
  #pragma unroll
  for (int i = 0; i < 4; ++i)
    #pragma unroll
    for (int j = 0; j < 5; ++j) t5c[i][j] = BIGF;

  float sqr_[16];
  #pragma unroll
  for (int mi = 0; mi < 4; ++mi)
    #pragma unroll
    for (int r = 0; r < 4; ++r)
      sqr_[mi * 4 + r] = sq[row0 + wr * 64 + mi * 16 + l4 * 4 + r];

  #pragma unroll
  for (int ni = 0; ni < 4; ++ni) {
    const int gc = cb + wc * 64 + ni * 16 + l15;
    const float sqc = sq[gc];
    #pragma unroll
    for (int mi = 0; mi < 4; ++mi) {
      #pragma unroll
      for (int r = 0; r < 4; ++r) {
        float v = fmaf(-2.0f, acc[mi][ni][r], sqr_[mi * 4 + r] + sqc);
        if (diag) {
          const int gr = row0 + wr * 64 + mi * 16 + l4 * 4 + r;
          v = (gc == gr) ? BIGF : v;  // exclude self
        }
        insert5(t5r[mi * 4 + r], v);
        if (!diag) insert5(t5c[ni], v);
      }
    }
  }

  // row-side merge, two passes of 64 rows; 4 threads/row (all 256 busy):
  // each merges 8 contributor lists, then shfl_xor(1,2) tree combines.
  #pragma unroll
  for (int pass = 0; pass < 2; ++pass) {
    __syncthreads();
    if (wr == pass) {
      #pragma unroll
      for (int mi = 0; mi < 4; ++mi)
        #pragma unroll
        for (int r = 0; r < 4; ++r)
          #pragma unroll
          for (int j = 0; j < 5; ++j)
            sh.mrg[(mi * 16 + l4 * 4 + r) * 160 + (wc * 16 + l15) * 5 + j] = t5r[mi * 4 + r][j];
    }
    __syncthreads();
    {
      const int rrow = tid >> 2, q = tid & 3;
      const float* base = &sh.mrg[rrow * 160 + q * 40];
      float m[5];
      #pragma unroll
      for (int j = 0; j < 5; ++j) m[j] = base[j];
      #pragma unroll
      for (int s2 = 1; s2 < 8; ++s2) {
        float b[5];
        #pragma unroll
        for (int j = 0; j < 5; ++j) b[j] = base[s2 * 5 + j];
        merge5(m, b);
      }
      #pragma unroll
      for (int off = 1; off <= 2; off <<= 1) {
        float o[5];
        #pragma unroll
        for (int j = 0; j < 5; ++j) o[j] = __shfl_xor(m[j], off, 64);
        merge5(m, o);
      }
      if (q == 0) {
        float* pp = partial + ((size_t)(row0 + pass * 64 + rrow) * NBv + J) * 5;
        #pragma unroll
        for (int j = 0; j < 5; ++j) pp[j] = m[j];
      }
    }
  }

  // col-side merge (128 cols; 8 contributors per col); 2 threads/col + shfl tree
  if (!diag) {
    __syncthreads();
    #pragma unroll
    for (int ni = 0; ni < 4; ++ni)
      #pragma unroll
      for (int j = 0; j < 5; ++j)
        sh.mrgc[(wc * 64 + ni * 16 + l15) * 41 + (wr * 4 + l4) * 5 + j] = t5c[ni][j];
    __syncthreads();
    {
      const int col = tid >> 1, q = tid & 1;
      const float* base = &sh.mrgc[col * 41 + q * 20];
      float m[5];
      #pragma unroll
      for (int j = 0; j < 5; ++j) m[j] = base[j];
      #pragma unroll
      for (int s2 = 1; s2 < 4; ++s2) {
        float b[5];
        #pragma unroll
        for (int j = 0; j < 5; ++j) b[j] = base[s2 * 5 + j];
        merge5(m, b);
      }
      float o[5];
      #pragma unroll
      for (int j = 0; j < 5; ++j) o[j] = __shfl_xor(m[j], 1, 64);
      merge5(m, o);
      if (q == 0) {
        float* pp = partial + ((size_t)(cb + col) * NBv + I) * 5;
        #pragma unroll
        for (int j = 0; j < 5; ++j) pp[j] = m[j];
      }
    }
  }
}

// fused weight+apply: one block per row. Wave 0 butterfly-merges the row's
// 64 slot-top5s -> w (broadcast via LDS); all 256 threads then scale the
// row's 256+256 float4 of xr/xi.
__global__ void apply_kernel(const float* __restrict__ xr, const float* __restrict__ xi,
                             const float* __restrict__ partial, float* __restrict__ out, int N) {
  __shared__ float wsh;
  const int row = blockIdx.x;
  const int tid = threadIdx.x;
  if (tid < 64) {
    const float* p = partial + ((size_t)row * 64 + tid) * 5;
    float t[5];
    #pragma unroll
    for (int j = 0; j < 5; ++j) t[j] = p[j];   // each slot sorted ascending
    #pragma unroll
    for (int off = 1; off < 64; off <<= 1) {
      float o[5];
      #pragma unroll
      for (int j = 0; j < 5; ++j) o[j] = __shfl_xor(t[j], off, 64);
      merge5(t, o);
    }
    if (tid == 0) {
      float sc = 0.f;
      #pragma unroll
      for (int j = 0; j < 5; ++j) sc += sqrtf(fmaxf(t[j], 0.f));
      sc *= 0.2f;  // mean of 5
      wsh = (sc > PTH) ? expf(-sc / TAU) : 0.f;
    }
  }
  const size_t i = (size_t)row * 256 + tid;
  const size_t tot = (size_t)N * (DD / 4);
  float4 a = reinterpret_cast<const float4*>(xr)[i];
  float4 b = reinterpret_cast<const float4*>(xi)[i];
  __syncthreads();
  const float wt = wsh;
  a.x *= wt; a.y *= wt; a.z *= wt; a.w *= wt;
  b.x *= wt; b.y *= wt; b.z *= wt; b.w *= wt;
  reinterpret_cast<float4*>(out)[i] = a;
  reinterpret_cast<float4*>(out)[tot + i] = b;
}

extern "C" void kernel_launch(void* const* d_in, const int* in_sizes, int n_in,
                              void* d_out, int out_size, void* d_ws, size_t ws_size,
                              hipStream_t stream) {
  const float* xr = (const float*)d_in[0];
  const float* xi = (const float*)d_in[1];
  float* out = (float*)d_out;
  const int N = in_sizes[0] / DD;  // 8192
  const int NBv = N / BM;          // 64
  const int NSB = NBv / 8;         // 8

  unsigned char* x8 = (unsigned char*)d_ws;                          // N*DD fp8 (8 MB)
  float* sq      = (float*)((char*)d_ws + (size_t)N * DD);           // N f32
  float* partial = sq + N;                                           // N*NBv*5 f32 (10.5 MB)

  prep_kernel<<<N / 4, 256, 0, stream>>>(xr, x8, sq);
  const int nsp = NSB * (NSB + 1) / 2;      // 36 super-pairs
  gemm_topk_kernel<<<nsp * 64, 256, 0, stream>>>(x8, sq, partial, N);  // 2304 blocks
  apply_kernel<<<N, 256, 0, stream>>>(xr, xi, partial, out, N);
}

// Round 25
// 97.582 us; speedup vs baseline: 1.1002x; 1.1002x over previous
//
#include <hip/hip_runtime.h>
#include <hip/hip_bf16.h>

#define DD 1024            // fp8 elems per row (= bytes)
#define BM 128
#define BN 128
#define BK 128             // fp8 elems per K-tile -> 128 B rows (proven geometry)
#define NKT (DD / BK)      // 8 K-tiles
#define TAU 32.0f
#define PTH 0.1f
#define BIGF 3.0e38f

typedef __attribute__((ext_vector_type(4))) float f32x4;
typedef __attribute__((ext_vector_type(2))) long i64x2;

// f32 -> OCP e4m3fn (RNE, saturate to 448, subnormal support)
__device__ __forceinline__ unsigned char f2e4m3(float f) {
  unsigned u = __float_as_uint(f);
  unsigned s = (u >> 24) & 0x80u;
  unsigned au = u & 0x7fffffffu;
  if (au >= 0x43E00000u) return (unsigned char)(s | 0x7E);     // clamp >= 448
  if (au < 0x3C800000u) {                                      // |f| < 2^-6: subnormal
    int m = (int)rintf(__uint_as_float(au) * 512.0f);          // steps of 2^-9
    if (m > 7) return (unsigned char)(s | 0x08);
    return (unsigned char)(s | (unsigned)m);
  }
  unsigned tmp = au + 0x0007FFFFu + ((au >> 20) & 1u);         // RNE at mantissa bit 20
  unsigned e4 = (tmp >> 23) - 120u;                            // rebias 127 -> 7
  if (e4 >= 16u) return (unsigned char)(s | 0x7E);
  return (unsigned char)(s | (e4 << 3) | ((tmp >> 20) & 7u));
}

// sorted-ascending top-5-smallest insert via med3: 5 independent VALU ops
__device__ __forceinline__ void insert5(float (&t)[5], float v) {
  float t0 = t[0], t1 = t[1], t2 = t[2], t3 = t[3], t4 = t[4];
  t[0] = fminf(t0, v);
  t[1] = __builtin_amdgcn_fmed3f(v, t0, t1);
  t[2] = __builtin_amdgcn_fmed3f(v, t1, t2);
  t[3] = __builtin_amdgcn_fmed3f(v, t2, t3);
  t[4] = __builtin_amdgcn_fmed3f(v, t3, t4);
}

// merge two ascending 5-lists -> ascending top-5 of union (~22 VALU):
// c_i = min(a_i, b_i, min_{j+k=i-1} max(a_j, b_k))
__device__ __forceinline__ void merge5(float (&a)[5], const float (&b)[5]) {
  float c0 = fminf(a[0], b[0]);
  float m00 = fmaxf(a[0], b[0]);
  float c1 = fminf(fminf(a[1], b[1]), m00);
  float m01 = fmaxf(a[0], b[1]), m10 = fmaxf(a[1], b[0]);
  float c2 = fminf(fminf(a[2], b[2]), fminf(m01, m10));
  float m02 = fmaxf(a[0], b[2]), m11 = fmaxf(a[1], b[1]), m20 = fmaxf(a[2], b[0]);
  float c3 = fminf(fminf(a[3], b[3]), fminf(fminf(m02, m11), m20));
  float m03 = fmaxf(a[0], b[3]), m12 = fmaxf(a[1], b[2]);
  float m21 = fmaxf(a[2], b[1]), m30 = fmaxf(a[3], b[0]);
  float c4 = fminf(fminf(a[4], b[4]), fminf(fminf(m03, m12), fminf(m21, m30)));
  a[0] = c0; a[1] = c1; a[2] = c2; a[3] = c3; a[4] = c4;
}

__device__ __forceinline__ void gload16(const unsigned char* g, unsigned char* l) {
  __builtin_amdgcn_global_load_lds(
      (const __attribute__((address_space(1))) void*)g,
      (__attribute__((address_space(3))) void*)l, 16, 0, 0);
}

// one wave per row: squared norm (f32, exact) + fp8 cast, K bit-field-permuted:
// within each 128-block, position p holds logical k with q[3:4]<->q[5:6] swapped
// (self-inverse; identical permutation on both GEMM operands => X.X^T unchanged).
__global__ void prep_kernel(const float* __restrict__ x, unsigned char* __restrict__ x8,
                            float* __restrict__ sq) {
  const int row  = blockIdx.x * 4 + (threadIdx.x >> 6);
  const int lane = threadIdx.x & 63;
  const float4* xr = reinterpret_cast<const float4*>(x) + (size_t)row * (DD / 4);
  float s = 0.f;
  #pragma unroll
  for (int i = 0; i < 4; ++i) {
    float4 v = xr[lane + 64 * i];
    s += v.x * v.x + v.y * v.y + v.z * v.z + v.w * v.w;
    uchar4 b;
    b.x = f2e4m3(v.x); b.y = f2e4m3(v.y); b.z = f2e4m3(v.z); b.w = f2e4m3(v.w);
    const int k0 = (lane + 64 * i) * 4;
    const int q  = k0 & 127;
    const int p  = (k0 & ~127) + ((q >> 3) & 3) * 32 + ((q >> 5) & 3) * 8 + (q & 7);
    *reinterpret_cast<uchar4*>(x8 + (size_t)row * DD + p) = b;
  }
  #pragma unroll
  for (int off = 32; off > 0; off >>= 1) s += __shfl_xor(s, off, 64);
  if (lane == 0) sq[row] = s;
}

// Symmetric flash top-k over upper-triangle 128x128 block-pairs (I,J), 8x8
// super-tiles + XCD swizzle. Single-buffer REGISTER pipeline + T5 setprio
// around the MFMA cluster. 3 blocks/CU (41.2KB LDS, stride-161 merge scratch
// = conflict-free; the 40KB/stride-160 variant (r24) gained no occupancy and
// tripled bank conflicts).
__global__ __launch_bounds__(256, 3)
void gemm_topk_kernel(const unsigned char* __restrict__ x8, const float* __restrict__ sq,
                      float* __restrict__ partial, int N) {
  __shared__ union ShMem {
    struct { unsigned char A[BM * BK]; unsigned char B[BN * BK]; } tl;  // 32 KB
    float mrg[64 * 161];   // row-merge: row*161 + contrib*5 + j  (41.2 KB)
    float mrgc[128 * 41];  // col-merge: col*41 + contrib*5 + j   (21 KB)
  } sh;
  static_assert(sizeof(ShMem) <= 65536, "LDS over 64KB");

  const int tid  = threadIdx.x;
  const int lane = tid & 63;
  const int wid  = tid >> 6;
  const int wr   = wid >> 1;   // 0..1 -> 64-row half
  const int wc   = wid & 1;    // 0..1 -> 64-col half
  const int l15  = lane & 15;
  const int l4   = lane >> 4;  // 0..3

  const int NBv = N / BM;      // 64 block-rows
  const int NSB = NBv / 8;     // 8 super-rows

  // bijective chunked XCD swizzle (gridDim.x divisible by 8)
  const int chunk = gridDim.x >> 3;
  const int swz = (blockIdx.x & 7) * chunk + (blockIdx.x >> 3);
  const int sp  = swz >> 6;    // super-pair (triangle over NSB)
  const int sub = swz & 63;

  int SI = 0;
  #define TSTART(i) ((i) * NSB - ((i) * ((i) - 1)) / 2)
  while (SI + 1 < NSB && TSTART(SI + 1) <= sp) ++SI;
  const int SJ = SI + (sp - TSTART(SI));
  #undef TSTART
  const int si = sub >> 3, sj = sub & 7;
  if (SI == SJ && si > sj) return;  // lower-triangle sub-pair of diagonal super-pair
  const int I = SI * 8 + si, J = SJ * 8 + sj;

  const int row0 = I * BM;
  const int cb   = J * BM;
  const bool diag = (I == J);

  // DMA staging: instruction j covers rows j*8..j*8+7 (1 KB linear LDS).
  // lane -> row j*8 + (lane>>3), phys slot lane&7 holds logical slot
  // (lane&7)^(row&7); row&7 == lane>>3.
  const int lr = lane >> 3;
  const int lc = (lane & 7) ^ lr;
  const size_t offl = (size_t)lr * DD + (size_t)lc * 16;
  const int jbase = wid * 4;
  const unsigned char* srcA = x8 + (size_t)row0 * DD + offl;
  const unsigned char* srcB = x8 + (size_t)cb * DD + offl;

  f32x4 acc[4][4];
  #pragma unroll
  for (int mi = 0; mi < 4; ++mi)
    #pragma unroll
    for (int ni = 0; ni < 4; ++ni) {
      f32x4 z; z[0] = 0.f; z[1] = 0.f; z[2] = 0.f; z[3] = 0.f;
      acc[mi][ni] = z;
    }

  // fragment reads: lane's 32 contiguous logical bytes at row*BK + l4*32,
  // as two b128 chunks c=0,1 at phys slot (l4*2+c)^(row&7); row&7 == l15&7
  const int ps0 = ((l4 * 2 + 0) ^ (l15 & 7)) * 16;
  const int ps1 = ((l4 * 2 + 1) ^ (l15 & 7)) * 16;

#define STAGE(kt) { const size_t kk = (size_t)(kt) * BK;                          \
    _Pragma("unroll") for (int jj = 0; jj < 4; ++jj) {                            \
      const int j = jbase + jj;                                                   \
      gload16(srcA + (size_t)j * 8 * DD + kk, sh.tl.A + j * 1024);                \
      gload16(srcB + (size_t)j * 8 * DD + kk, sh.tl.B + j * 1024); } }

  // prologue: stage tile 0
  STAGE(0);

  for (int t = 0; t < NKT; ++t) {
    __syncthreads();   // vmcnt drain: tile t landed (issued last iter / prologue)

    // read ALL fragments of tile t into registers
    i64x2 af[4][2], bfr[4][2];
    #pragma unroll
    for (int mi = 0; mi < 4; ++mi) {
      const unsigned char* rp = sh.tl.A + (wr * 64 + mi * 16 + l15) * BK;
      af[mi][0] = *reinterpret_cast<const i64x2*>(rp + ps0);
      af[mi][1] = *reinterpret_cast<const i64x2*>(rp + ps1);
    }
    #pragma unroll
    for (int ni = 0; ni < 4; ++ni) {
      const unsigned char* rp = sh.tl.B + (wc * 64 + ni * 16 + l15) * BK;
      bfr[ni][0] = *reinterpret_cast<const i64x2*>(rp + ps0);
      bfr[ni][1] = *reinterpret_cast<const i64x2*>(rp + ps1);
    }

    __syncthreads();   // lgkm drain: all waves' fragment reads done -> buffer free

    if (t + 1 < NKT) STAGE(t + 1);  // DMA issues BEFORE the MFMA cluster: latency hides

    __builtin_amdgcn_s_setprio(1);  // favor MFMA-issuing waves vs co-resident stagers
    #pragma unroll
    for (int ks = 0; ks < 4; ++ks)
      #pragma unroll
      for (int mi = 0; mi < 4; ++mi)
        #pragma unroll
        for (int ni = 0; ni < 4; ++ni)
          acc[mi][ni] = __builtin_amdgcn_mfma_f32_16x16x32_fp8_fp8(
              af[mi][ks >> 1][ks & 1], bfr[ni][ks >> 1][ks & 1], acc[mi][ni], 0, 0, 0);
    __builtin_amdgcn_s_setprio(0);
  }

  // d^2 = sq_r + sq_c - 2*dot; fold row-side (t5r) and, off-diag, col-side (t5c)
  float t5r[16][5], t5c[4][5];
  #pragma unroll
  for (int i = 0; i < 16; ++i)
    #pragma unroll
    for (int j = 0; j < 5; ++j) t5r[i][j] = BIGF;
  #pragma unroll
  for (int i = 0; i < 4; ++i)
    #pragma unroll
    for (int j = 0; j < 5; ++j) t5c[i][j] = BIGF;

  float sqr_[16];
  #pragma unroll
  for (int mi = 0; mi < 4; ++mi)
    #pragma unroll
    for (int r = 0; r < 4; ++r)
      sqr_[mi * 4 + r] = sq[row0 + wr * 64 + mi * 16 + l4 * 4 + r];

  #pragma unroll
  for (int ni = 0; ni < 4; ++ni) {
    const int gc = cb + wc * 64 + ni * 16 + l15;
    const float sqc = sq[gc];
    #pragma unroll
    for (int mi = 0; mi < 4; ++mi) {
      #pragma unroll
      for (int r = 0; r < 4; ++r) {
        float v = fmaf(-2.0f, acc[mi][ni][r], sqr_[mi * 4 + r] + sqc);
        if (diag) {
          const int gr = row0 + wr * 64 + mi * 16 + l4 * 4 + r;
          v = (gc == gr) ? BIGF : v;  // exclude self
        }
        insert5(t5r[mi * 4 + r], v);
        if (!diag) insert5(t5c[ni], v);
      }
    }
  }

  // row-side merge, two passes of 64 rows; 4 threads/row (all 256 busy):
  // each merges 8 contributor lists, then shfl_xor(1,2) tree combines.
  #pragma unroll
  for (int pass = 0; pass < 2; ++pass) {
    __syncthreads();
    if (wr == pass) {
      #pragma unroll
      for (int mi = 0; mi < 4; ++mi)
        #pragma unroll
        for (int r = 0; r < 4; ++r)
          #pragma unroll
          for (int j = 0; j < 5; ++j)
            sh.mrg[(mi * 16 + l4 * 4 + r) * 161 + (wc * 16 + l15) * 5 + j] = t5r[mi * 4 + r][j];
    }
    __syncthreads();
    {
      const int rrow = tid >> 2, q = tid & 3;
      const float* base = &sh.mrg[rrow * 161 + q * 40];
      float m[5];
      #pragma unroll
      for (int j = 0; j < 5; ++j) m[j] = base[j];
      #pragma unroll
      for (int s2 = 1; s2 < 8; ++s2) {
        float b[5];
        #pragma unroll
        for (int j = 0; j < 5; ++j) b[j] = base[s2 * 5 + j];
        merge5(m, b);
      }
      #pragma unroll
      for (int off = 1; off <= 2; off <<= 1) {
        float o[5];
        #pragma unroll
        for (int j = 0; j < 5; ++j) o[j] = __shfl_xor(m[j], off, 64);
        merge5(m, o);
      }
      if (q == 0) {
        float* pp = partial + ((size_t)(row0 + pass * 64 + rrow) * NBv + J) * 5;
        #pragma unroll
        for (int j = 0; j < 5; ++j) pp[j] = m[j];
      }
    }
  }

  // col-side merge (128 cols; 8 contributors per col); 2 threads/col + shfl tree
  if (!diag) {
    __syncthreads();
    #pragma unroll
    for (int ni = 0; ni < 4; ++ni)
      #pragma unroll
      for (int j = 0; j < 5; ++j)
        sh.mrgc[(wc * 64 + ni * 16 + l15) * 41 + (wr * 4 + l4) * 5 + j] = t5c[ni][j];
    __syncthreads();
    {
      const int col = tid >> 1, q = tid & 1;
      const float* base = &sh.mrgc[col * 41 + q * 20];
      float m[5];
      #pragma unroll
      for (int j = 0; j < 5; ++j) m[j] = base[j];
      #pragma unroll
      for (int s2 = 1; s2 < 4; ++s2) {
        float b[5];
        #pragma unroll
        for (int j = 0; j < 5; ++j) b[j] = base[s2 * 5 + j];
        merge5(m, b);
      }
      float o[5];
      #pragma unroll
      for (int j = 0; j < 5; ++j) o[j] = __shfl_xor(m[j], 1, 64);
      merge5(m, o);
      if (q == 0) {
        float* pp = partial + ((size_t)(cb + col) * NBv + I) * 5;
        #pragma unroll
        for (int j = 0; j < 5; ++j) pp[j] = m[j];
      }
    }
  }
}

// fused weight+apply: one block per row. Wave 0 butterfly-merges the row's
// 64 slot-top5s -> w (broadcast via LDS); all 256 threads then scale the
// row's 256+256 float4 of xr/xi.
__global__ void apply_kernel(const float* __restrict__ xr, const float* __restrict__ xi,
                             const float* __restrict__ partial, float* __restrict__ out, int N) {
  __shared__ float wsh;
  const int row = blockIdx.x;
  const int tid = threadIdx.x;
  if (tid < 64) {
    const float* p = partial + ((size_t)row * 64 + tid) * 5;
    float t[5];
    #pragma unroll
    for (int j = 0; j < 5; ++j) t[j] = p[j];   // each slot sorted ascending
    #pragma unroll
    for (int off = 1; off < 64; off <<= 1) {
      float o[5];
      #pragma unroll
      for (int j = 0; j < 5; ++j) o[j] = __shfl_xor(t[j], off, 64);
      merge5(t, o);
    }
    if (tid == 0) {
      float sc = 0.f;
      #pragma unroll
      for (int j = 0; j < 5; ++j) sc += sqrtf(fmaxf(t[j], 0.f));
      sc *= 0.2f;  // mean of 5
      wsh = (sc > PTH) ? expf(-sc / TAU) : 0.f;
    }
  }
  const size_t i = (size_t)row * 256 + tid;
  const size_t tot = (size_t)N * (DD / 4);
  float4 a = reinterpret_cast<const float4*>(xr)[i];
  float4 b = reinterpret_cast<const float4*>(xi)[i];
  __syncthreads();
  const float wt = wsh;
  a.x *= wt; a.y *= wt; a.z *= wt; a.w *= wt;
  b.x *= wt; b.y *= wt; b.z *= wt; b.w *= wt;
  reinterpret_cast<float4*>(out)[i] = a;
  reinterpret_cast<float4*>(out)[tot + i] = b;
}

extern "C" void kernel_launch(void* const* d_in, const int* in_sizes, int n_in,
                              void* d_out, int out_size, void* d_ws, size_t ws_size,
                              hipStream_t stream) {
  const float* xr = (const float*)d_in[0];
  const float* xi = (const float*)d_in[1];
  float* out = (float*)d_out;
  const int N = in_sizes[0] / DD;  // 8192
  const int NBv = N / BM;          // 64
  const int NSB = NBv / 8;         // 8

  unsigned char* x8 = (unsigned char*)d_ws;                          // N*DD fp8 (8 MB)
  float* sq      = (float*)((char*)d_ws + (size_t)N * DD);           // N f32
  float* partial = sq + N;                                           // N*NBv*5 f32 (10.5 MB)

  prep_kernel<<<N / 4, 256, 0, stream>>>(xr, x8, sq);
  const int nsp = NSB * (NSB + 1) / 2;      // 36 super-pairs
  gemm_topk_kernel<<<nsp * 64, 256, 0, stream>>>(x8, sq, partial, N);  // 2304 blocks
  apply_kernel<<<N, 256, 0, stream>>>(xr, xi, partial, out, N);
}